// Round 1
// baseline (2416.202 us; speedup 1.0000x reference)
//
#include <hip/hip_runtime.h>

#define EPS 1e-6f

constexpr int N_ = 8;
constexpr int H_ = 720;
constexpr int W_ = 1280;
constexpr int NPIX = N_ * H_ * W_;   // 7,372,800

__global__ void splat_kernel(const float* __restrict__ img,
                             const float* __restrict__ counts,
                             const float* __restrict__ flo,
                             float* __restrict__ acc_img,
                             float* __restrict__ acc_one) {
    int idx = blockIdx.x * blockDim.x + threadIdx.x;
    if (idx >= NPIX) return;

    int w = idx % W_;
    int t = idx / W_;
    int h = t % H_;
    int n = t / H_;

    float iv = img[idx];
    float cv = counts[idx];

    // flo layout: (N, 2, H, W); channel 0 = y (shifts W axis), channel 1 = x (shifts H axis)
    int fbase = ((n * 2) * H_ + h) * W_ + w;
    float y = flo[fbase];
    float x = flo[fbase + H_ * W_];

    float x1 = floorf(x);
    float y1 = floorf(y);
    float fx = x - x1;          // in [0,1)
    float fy = y - y1;

    // exp(-(dx^2+dy^2)) = exp(-dx^2)*exp(-dy^2)
    float ex1 = __expf(-fx * fx);
    float gx  = 1.0f - fx;
    float ex2 = __expf(-gx * gx);
    float ey1 = __expf(-fy * fy);
    float gy  = 1.0f - fy;
    float ey2 = __expf(-gy * gy);

    float w11 = ex1 * ey1;
    float w12 = ex1 * ey2;
    float w21 = ex2 * ey1;
    float w22 = ex2 * ey2;
    float s = w11 + w12 + w21 + w22;
    float inv = cv / s;          // fold counts into the normalization
    w11 *= inv; w12 *= inv; w21 *= inv; w22 *= inv;

    int ix1 = (int)x1 + h;       // row target
    int ix2 = ix1 + 1;
    int iy1 = (int)y1 + w;       // col target
    int iy2 = iy1 + 1;

    bool vx1 = (unsigned)ix1 < (unsigned)H_;
    bool vx2 = (unsigned)ix2 < (unsigned)H_;
    bool vy1 = (unsigned)iy1 < (unsigned)W_;
    bool vy2 = (unsigned)iy2 < (unsigned)W_;

    int nbase = n * (H_ * W_);
    if (vx1 && vy1) {
        int o = nbase + ix1 * W_ + iy1;
        atomicAdd(acc_img + o, iv * w11);
        atomicAdd(acc_one + o, w11);
    }
    if (vx1 && vy2) {
        int o = nbase + ix1 * W_ + iy2;
        atomicAdd(acc_img + o, iv * w12);
        atomicAdd(acc_one + o, w12);
    }
    if (vx2 && vy1) {
        int o = nbase + ix2 * W_ + iy1;
        atomicAdd(acc_img + o, iv * w21);
        atomicAdd(acc_one + o, w21);
    }
    if (vx2 && vy2) {
        int o = nbase + ix2 * W_ + iy2;
        atomicAdd(acc_img + o, iv * w22);
        atomicAdd(acc_one + o, w22);
    }
}

__global__ void finalize_kernel(float* __restrict__ out0,
                                const float* __restrict__ out1) {
    int idx = blockIdx.x * blockDim.x + threadIdx.x;
    if (idx >= NPIX) return;
    out0[idx] = out0[idx] / (out1[idx] + EPS);
}

extern "C" void kernel_launch(void* const* d_in, const int* in_sizes, int n_in,
                              void* d_out, int out_size, void* d_ws, size_t ws_size,
                              hipStream_t stream) {
    const float* img    = (const float*)d_in[0];
    const float* counts = (const float*)d_in[1];
    const float* flo    = (const float*)d_in[2];

    float* out0 = (float*)d_out;        // imgw accumulator -> normalized image
    float* out1 = out0 + NPIX;          // o accumulator (raw second output)

    // d_out is poisoned to 0xAA before every call; zero both accumulator planes.
    hipMemsetAsync(d_out, 0, (size_t)2 * NPIX * sizeof(float), stream);

    const int threads = 256;
    const int blocks = (NPIX + threads - 1) / threads;
    splat_kernel<<<blocks, threads, 0, stream>>>(img, counts, flo, out0, out1);
    finalize_kernel<<<blocks, threads, 0, stream>>>(out0, out1);
}

// Round 2
// 2416.180 us; speedup vs baseline: 1.0000x; 1.0000x over previous
//
#include <hip/hip_runtime.h>

#define EPS 1e-6f

constexpr int N_ = 8;
constexpr int H_ = 720;
constexpr int W_ = 1280;
constexpr int NPIX = N_ * H_ * W_;   // 7,372,800

// Tiling for the privatized splat
constexpr int TH = 40;               // tile rows   (720 = 18*40, exact)
constexpr int TW = 40;               // tile cols   (1280 = 32*40, exact)
constexpr int R_ = 24;               // halo = 3 sigma of the sigma=8 flow
constexpr int LH = TH + 2 * R_;      // 88
constexpr int LW = TW + 2 * R_;      // 88
constexpr int LSZ = LH * LW;         // 7744 positions
constexpr int TILES_H = H_ / TH;     // 18
constexpr int TILES_W = W_ / TW;     // 32
constexpr int NTILES = N_ * TILES_H * TILES_W;          // 4608
constexpr size_t WS_NEEDED = (size_t)NTILES * LSZ * 2 * sizeof(float); // ~272 MiB

// ---------------------------------------------------------------------------
// Phase A: per-tile privatized splat. One block = one 40x40 source tile.
// LDS holds interleaved {img_acc, one_acc} for the 88x88 halo'd tile.
// Out-of-halo splats (rare, ~3sigma tail) go straight to d_out via atomics.
// LDS result is dumped to a PRIVATE region of ws with plain stores.
// ---------------------------------------------------------------------------
__global__ __launch_bounds__(512) void splat_tiled_kernel(
        const float* __restrict__ img,
        const float* __restrict__ counts,
        const float* __restrict__ flo,
        float* __restrict__ ws,          // NTILES * LSZ * 2 floats
        float* __restrict__ fb_img,      // fallback accumulators = d_out planes
        float* __restrict__ fb_one) {
    __shared__ float4 lds4[LSZ / 2];     // 7744*2 floats = 61952 B
    float* lds = (float*)lds4;

    int bt = blockIdx.x;                 // ((n*TILES_H + tr)*TILES_W + tc)
    int tc = bt % TILES_W;
    int t2 = bt / TILES_W;
    int tr = t2 % TILES_H;
    int n  = t2 / TILES_H;
    int row0 = tr * TH;
    int col0 = tc * TW;
    int tid = threadIdx.x;

    // zero LDS
    for (int i = tid; i < LSZ / 2; i += 512)
        lds4[i] = make_float4(0.f, 0.f, 0.f, 0.f);
    __syncthreads();

    int nbase = n * (H_ * W_);
    int fbase_n = n * 2 * (H_ * W_);

    for (int p = tid; p < TH * TW; p += 512) {
        int r = p / TW;
        int c = p % TW;
        int h = row0 + r;
        int w = col0 + c;
        int idx = nbase + h * W_ + w;

        float iv = img[idx];
        float cv = counts[idx];
        int fo = fbase_n + h * W_ + w;
        float y = flo[fo];                 // channel 0 shifts W axis
        float x = flo[fo + H_ * W_];       // channel 1 shifts H axis

        float x1 = floorf(x);
        float y1 = floorf(y);
        float fx = x - x1;
        float fy = y - y1;
        float gx = 1.0f - fx;
        float gy = 1.0f - fy;
        float ex1 = __expf(-fx * fx);
        float ex2 = __expf(-gx * gx);
        float ey1 = __expf(-fy * fy);
        float ey2 = __expf(-gy * gy);

        float s = (ex1 + ex2) * (ey1 + ey2);
        float inv = cv / s;

        int ix1 = (int)x1 + h;
        int iy1 = (int)y1 + w;

        int ixr[2] = {ix1, ix1 + 1};
        int iyc[2] = {iy1, iy1 + 1};
        float wx[2] = {ex1, ex2};
        float wy[2] = {ey1, ey2};

        #pragma unroll
        for (int a = 0; a < 2; ++a) {
            #pragma unroll
            for (int b = 0; b < 2; ++b) {
                float ww = wx[a] * wy[b] * inv;
                float wi = iv * ww;
                int lh = ixr[a] - row0 + R_;
                int lw = iyc[b] - col0 + R_;
                if ((unsigned)lh < (unsigned)LH && (unsigned)lw < (unsigned)LW) {
                    int o = (lh * LW + lw) * 2;
                    atomicAdd(lds + o,     wi);   // ds_add_f32
                    atomicAdd(lds + o + 1, ww);
                } else if ((unsigned)ixr[a] < (unsigned)H_ &&
                           (unsigned)iyc[b] < (unsigned)W_) {
                    int o = nbase + ixr[a] * W_ + iyc[b];
                    atomicAdd(fb_img + o, wi);    // rare: ~3sigma tail
                    atomicAdd(fb_one + o, ww);
                }
            }
        }
    }
    __syncthreads();

    // private, coalesced dump: no atomics
    float4* wsb = (float4*)(ws + (size_t)bt * LSZ * 2);
    for (int i = tid; i < LSZ / 2; i += 512)
        wsb[i] = lds4[i];
}

// ---------------------------------------------------------------------------
// Phase B: gather. Each output pixel sums the <=2x2 covering tile buffers
// plus the rare fallback contributions already atomically added into d_out.
// ---------------------------------------------------------------------------
__global__ __launch_bounds__(256) void gather_kernel(
        const float* __restrict__ ws,
        float* __restrict__ out0,
        float* __restrict__ out1) {
    int idx = blockIdx.x * blockDim.x + threadIdx.x;
    if (idx >= NPIX) return;
    int w = idx % W_;
    int t = idx / W_;
    int h = t % H_;
    int n = t / H_;

    float fimg = out0[idx];   // fallback accumulation (usually 0)
    float fone = out1[idx];

    int tr_lo = (h >= R_) ? (h - R_) / TH : 0;
    int tr_hi = (h + R_) / TH; if (tr_hi > TILES_H - 1) tr_hi = TILES_H - 1;
    int tc_lo = (w >= R_) ? (w - R_) / TW : 0;
    int tc_hi = (w + R_) / TW; if (tc_hi > TILES_W - 1) tc_hi = TILES_W - 1;

    for (int tr = tr_lo; tr <= tr_hi; ++tr) {
        int lh = h - tr * TH + R_;
        for (int tc = tc_lo; tc <= tc_hi; ++tc) {
            int lw = w - tc * TW + R_;
            size_t base = ((size_t)((n * TILES_H + tr) * TILES_W + tc)) * LSZ * 2;
            const float2 v = *(const float2*)(ws + base + (size_t)(lh * LW + lw) * 2);
            fimg += v.x;
            fone += v.y;
        }
    }
    out0[idx] = fimg / (fone + EPS);
    out1[idx] = fone;
}

// ---------------------------------------------------------------------------
// Fallback path (ws too small): direct-atomic version (round-1, correct).
// ---------------------------------------------------------------------------
__global__ void splat_atomic_kernel(const float* __restrict__ img,
                                    const float* __restrict__ counts,
                                    const float* __restrict__ flo,
                                    float* __restrict__ acc_img,
                                    float* __restrict__ acc_one) {
    int idx = blockIdx.x * blockDim.x + threadIdx.x;
    if (idx >= NPIX) return;
    int w = idx % W_;
    int t = idx / W_;
    int h = t % H_;
    int n = t / H_;

    float iv = img[idx];
    float cv = counts[idx];
    int fbase = ((n * 2) * H_ + h) * W_ + w;
    float y = flo[fbase];
    float x = flo[fbase + H_ * W_];

    float x1 = floorf(x);
    float y1 = floorf(y);
    float fx = x - x1, fy = y - y1;
    float gx = 1.0f - fx, gy = 1.0f - fy;
    float ex1 = __expf(-fx * fx), ex2 = __expf(-gx * gx);
    float ey1 = __expf(-fy * fy), ey2 = __expf(-gy * gy);
    float s = (ex1 + ex2) * (ey1 + ey2);
    float inv = cv / s;

    int ix1 = (int)x1 + h, ix2 = ix1 + 1;
    int iy1 = (int)y1 + w, iy2 = iy1 + 1;
    int nbase = n * (H_ * W_);
    if ((unsigned)ix1 < (unsigned)H_ && (unsigned)iy1 < (unsigned)W_) {
        int o = nbase + ix1 * W_ + iy1; float ww = ex1 * ey1 * inv;
        atomicAdd(acc_img + o, iv * ww); atomicAdd(acc_one + o, ww);
    }
    if ((unsigned)ix1 < (unsigned)H_ && (unsigned)iy2 < (unsigned)W_) {
        int o = nbase + ix1 * W_ + iy2; float ww = ex1 * ey2 * inv;
        atomicAdd(acc_img + o, iv * ww); atomicAdd(acc_one + o, ww);
    }
    if ((unsigned)ix2 < (unsigned)H_ && (unsigned)iy1 < (unsigned)W_) {
        int o = nbase + ix2 * W_ + iy1; float ww = ex2 * ey1 * inv;
        atomicAdd(acc_img + o, iv * ww); atomicAdd(acc_one + o, ww);
    }
    if ((unsigned)ix2 < (unsigned)H_ && (unsigned)iy2 < (unsigned)W_) {
        int o = nbase + ix2 * W_ + iy2; float ww = ex2 * ey2 * inv;
        atomicAdd(acc_img + o, iv * ww); atomicAdd(acc_one + o, ww);
    }
}

__global__ void finalize_kernel(float* __restrict__ out0,
                                const float* __restrict__ out1) {
    int idx = blockIdx.x * blockDim.x + threadIdx.x;
    if (idx >= NPIX) return;
    out0[idx] = out0[idx] / (out1[idx] + EPS);
}

extern "C" void kernel_launch(void* const* d_in, const int* in_sizes, int n_in,
                              void* d_out, int out_size, void* d_ws, size_t ws_size,
                              hipStream_t stream) {
    const float* img    = (const float*)d_in[0];
    const float* counts = (const float*)d_in[1];
    const float* flo    = (const float*)d_in[2];

    float* out0 = (float*)d_out;
    float* out1 = out0 + NPIX;

    // d_out is re-poisoned before every call; both planes double as
    // fallback atomic accumulators -> zero them.
    hipMemsetAsync(d_out, 0, (size_t)2 * NPIX * sizeof(float), stream);

    if (ws_size >= WS_NEEDED) {
        float* ws = (float*)d_ws;   // fully overwritten by phase A; no pre-zero
        splat_tiled_kernel<<<NTILES, 512, 0, stream>>>(img, counts, flo, ws,
                                                       out0, out1);
        gather_kernel<<<(NPIX + 255) / 256, 256, 0, stream>>>(ws, out0, out1);
    } else {
        const int threads = 256;
        const int blocks = (NPIX + threads - 1) / threads;
        splat_atomic_kernel<<<blocks, threads, 0, stream>>>(img, counts, flo,
                                                            out0, out1);
        finalize_kernel<<<blocks, threads, 0, stream>>>(out0, out1);
    }
}

// Round 3
// 552.867 us; speedup vs baseline: 4.3703x; 4.3703x over previous
//
#include <hip/hip_runtime.h>

#define EPS 1e-6f

constexpr int N_ = 8;
constexpr int H_ = 720;
constexpr int W_ = 1280;
constexpr int HW = H_ * W_;
constexpr int NPIX = N_ * HW;        // 7,372,800

// Tiling for the privatized splat
constexpr int TH = 40;               // tile rows   (720 = 18*40, exact)
constexpr int TW = 40;               // tile cols   (1280 = 32*40, exact)
constexpr int R_ = 24;               // halo = 3 sigma of the sigma=8 flow
constexpr int LH = TH + 2 * R_;      // 88
constexpr int LW = TW + 2 * R_;      // 88
constexpr int LSZ = LH * LW;         // 7744 positions
constexpr int TILES_H = H_ / TH;     // 18
constexpr int TILES_W = W_ / TW;     // 32
constexpr int TILES_PER_IMG = TILES_H * TILES_W;        // 576
constexpr size_t WS_PER_IMG = (size_t)TILES_PER_IMG * LSZ * 2 * sizeof(float); // ~34 MiB

// ---------------------------------------------------------------------------
// Phase A: per-tile privatized splat for images [n0, n0+ni). One block = one
// 40x40 source tile. LDS holds interleaved {img_acc, one_acc} for the 88x88
// halo'd tile. Out-of-halo splats (~1e-3 of pixels) go to d_out via global
// atomics. LDS result is dumped to a PRIVATE chunk-local ws region with
// plain coalesced stores — zero atomics on the hot path.
// ---------------------------------------------------------------------------
__global__ __launch_bounds__(512) void splat_tiled_kernel(
        const float* __restrict__ img,
        const float* __restrict__ counts,
        const float* __restrict__ flo,
        float* __restrict__ ws,          // ni * 576 * LSZ * 2 floats
        float* __restrict__ fb_img,      // fallback accumulators = d_out planes
        float* __restrict__ fb_one,
        int n0) {
    __shared__ float4 lds4[LSZ / 2];     // 7744*2 floats = 61952 B
    float* lds = (float*)lds4;

    int bt = blockIdx.x;                 // chunk-local tile id
    int tc = bt % TILES_W;
    int t2 = bt / TILES_W;
    int tr = t2 % TILES_H;
    int n  = n0 + t2 / TILES_H;
    int row0 = tr * TH;
    int col0 = tc * TW;
    int tid = threadIdx.x;

    // zero LDS
    for (int i = tid; i < LSZ / 2; i += 512)
        lds4[i] = make_float4(0.f, 0.f, 0.f, 0.f);
    __syncthreads();

    int nbase = n * HW;
    int fbase_n = n * 2 * HW;

    for (int p = tid; p < TH * TW; p += 512) {
        int r = p / TW;
        int c = p % TW;
        int h = row0 + r;
        int w = col0 + c;
        int idx = nbase + h * W_ + w;

        float iv = img[idx];
        float cv = counts[idx];
        int fo = fbase_n + h * W_ + w;
        float y = flo[fo];                 // channel 0 shifts W axis
        float x = flo[fo + HW];            // channel 1 shifts H axis

        float x1 = floorf(x);
        float y1 = floorf(y);
        float fx = x - x1;
        float fy = y - y1;
        float gx = 1.0f - fx;
        float gy = 1.0f - fy;
        float ex1 = __expf(-fx * fx);
        float ex2 = __expf(-gx * gx);
        float ey1 = __expf(-fy * fy);
        float ey2 = __expf(-gy * gy);

        float s = (ex1 + ex2) * (ey1 + ey2);
        float inv = cv / s;

        int ix1 = (int)x1 + h;
        int iy1 = (int)y1 + w;

        int ixr[2] = {ix1, ix1 + 1};
        int iyc[2] = {iy1, iy1 + 1};
        float wx[2] = {ex1, ex2};
        float wy[2] = {ey1, ey2};

        #pragma unroll
        for (int a = 0; a < 2; ++a) {
            #pragma unroll
            for (int b = 0; b < 2; ++b) {
                float ww = wx[a] * wy[b] * inv;
                float wi = iv * ww;
                int lh = ixr[a] - row0 + R_;
                int lw = iyc[b] - col0 + R_;
                if ((unsigned)lh < (unsigned)LH && (unsigned)lw < (unsigned)LW) {
                    int o = (lh * LW + lw) * 2;
                    atomicAdd(lds + o,     wi);   // ds_add_f32
                    atomicAdd(lds + o + 1, ww);
                } else if ((unsigned)ixr[a] < (unsigned)H_ &&
                           (unsigned)iyc[b] < (unsigned)W_) {
                    int o = nbase + ixr[a] * W_ + iyc[b];
                    atomicAdd(fb_img + o, wi);    // rare: ~3sigma tail
                    atomicAdd(fb_one + o, ww);
                }
            }
        }
    }
    __syncthreads();

    // private, coalesced dump: no atomics
    float4* wsb = (float4*)(ws + (size_t)bt * LSZ * 2);
    for (int i = tid; i < LSZ / 2; i += 512)
        wsb[i] = lds4[i];
}

// ---------------------------------------------------------------------------
// Phase B: gather for images [n0, n0+ni). Each output pixel sums the tile
// buffers whose halo'd window covers it (<=9, typically 4) plus the rare
// fallback contributions already atomically added into d_out.
// ---------------------------------------------------------------------------
__global__ __launch_bounds__(256) void gather_kernel(
        const float* __restrict__ ws,
        float* __restrict__ out0,
        float* __restrict__ out1,
        int n0, int npix_chunk) {
    int lidx = blockIdx.x * blockDim.x + threadIdx.x;
    if (lidx >= npix_chunk) return;
    int w = lidx % W_;
    int t = lidx / W_;
    int h = t % H_;
    int nl = t / H_;                  // chunk-local image index

    int gidx = (n0 + nl) * HW + h * W_ + w;

    float fimg = out0[gidx];   // fallback accumulation (usually 0)
    float fone = out1[gidx];

    int tr_lo = (h >= R_) ? (h - R_) / TH : 0;
    int tr_hi = (h + R_) / TH; if (tr_hi > TILES_H - 1) tr_hi = TILES_H - 1;
    int tc_lo = (w >= R_) ? (w - R_) / TW : 0;
    int tc_hi = (w + R_) / TW; if (tc_hi > TILES_W - 1) tc_hi = TILES_W - 1;

    for (int tr = tr_lo; tr <= tr_hi; ++tr) {
        int lh = h - tr * TH + R_;
        for (int tc = tc_lo; tc <= tc_hi; ++tc) {
            int lw = w - tc * TW + R_;
            size_t base = ((size_t)((nl * TILES_H + tr) * TILES_W + tc)) * (LSZ * 2);
            const float2 v = *(const float2*)(ws + base + (size_t)(lh * LW + lw) * 2);
            fimg += v.x;
            fone += v.y;
        }
    }
    out0[gidx] = fimg / (fone + EPS);
    out1[gidx] = fone;
}

// ---------------------------------------------------------------------------
// Fallback path (ws smaller than one image's tiles): direct-atomic version.
// ---------------------------------------------------------------------------
__global__ void splat_atomic_kernel(const float* __restrict__ img,
                                    const float* __restrict__ counts,
                                    const float* __restrict__ flo,
                                    float* __restrict__ acc_img,
                                    float* __restrict__ acc_one) {
    int idx = blockIdx.x * blockDim.x + threadIdx.x;
    if (idx >= NPIX) return;
    int w = idx % W_;
    int t = idx / W_;
    int h = t % H_;
    int n = t / H_;

    float iv = img[idx];
    float cv = counts[idx];
    int fbase = ((n * 2) * H_ + h) * W_ + w;
    float y = flo[fbase];
    float x = flo[fbase + HW];

    float x1 = floorf(x);
    float y1 = floorf(y);
    float fx = x - x1, fy = y - y1;
    float gx = 1.0f - fx, gy = 1.0f - fy;
    float ex1 = __expf(-fx * fx), ex2 = __expf(-gx * gx);
    float ey1 = __expf(-fy * fy), ey2 = __expf(-gy * gy);
    float s = (ex1 + ex2) * (ey1 + ey2);
    float inv = cv / s;

    int ix1 = (int)x1 + h, ix2 = ix1 + 1;
    int iy1 = (int)y1 + w, iy2 = iy1 + 1;
    int nbase = n * HW;
    if ((unsigned)ix1 < (unsigned)H_ && (unsigned)iy1 < (unsigned)W_) {
        int o = nbase + ix1 * W_ + iy1; float ww = ex1 * ey1 * inv;
        atomicAdd(acc_img + o, iv * ww); atomicAdd(acc_one + o, ww);
    }
    if ((unsigned)ix1 < (unsigned)H_ && (unsigned)iy2 < (unsigned)W_) {
        int o = nbase + ix1 * W_ + iy2; float ww = ex1 * ey2 * inv;
        atomicAdd(acc_img + o, iv * ww); atomicAdd(acc_one + o, ww);
    }
    if ((unsigned)ix2 < (unsigned)H_ && (unsigned)iy1 < (unsigned)W_) {
        int o = nbase + ix2 * W_ + iy1; float ww = ex2 * ey1 * inv;
        atomicAdd(acc_img + o, iv * ww); atomicAdd(acc_one + o, ww);
    }
    if ((unsigned)ix2 < (unsigned)H_ && (unsigned)iy2 < (unsigned)W_) {
        int o = nbase + ix2 * W_ + iy2; float ww = ex2 * ey2 * inv;
        atomicAdd(acc_img + o, iv * ww); atomicAdd(acc_one + o, ww);
    }
}

__global__ void finalize_kernel(float* __restrict__ out0,
                                const float* __restrict__ out1) {
    int idx = blockIdx.x * blockDim.x + threadIdx.x;
    if (idx >= NPIX) return;
    out0[idx] = out0[idx] / (out1[idx] + EPS);
}

extern "C" void kernel_launch(void* const* d_in, const int* in_sizes, int n_in,
                              void* d_out, int out_size, void* d_ws, size_t ws_size,
                              hipStream_t stream) {
    const float* img    = (const float*)d_in[0];
    const float* counts = (const float*)d_in[1];
    const float* flo    = (const float*)d_in[2];

    float* out0 = (float*)d_out;
    float* out1 = out0 + NPIX;

    // d_out is re-poisoned before every call; both planes double as
    // fallback atomic accumulators -> zero them.
    hipMemsetAsync(d_out, 0, (size_t)2 * NPIX * sizeof(float), stream);

    // images per chunk, limited by workspace (34 MiB per image of tiles)
    int ipc = (int)(ws_size / WS_PER_IMG);
    if (ipc > N_) ipc = N_;

    if (ipc >= 1) {
        float* ws = (float*)d_ws;  // one chunk region, reused (stream-serialized)
        for (int n0 = 0; n0 < N_; n0 += ipc) {
            int ni = (n0 + ipc <= N_) ? ipc : (N_ - n0);
            splat_tiled_kernel<<<ni * TILES_PER_IMG, 512, 0, stream>>>(
                img, counts, flo, ws, out0, out1, n0);
            int npix_chunk = ni * HW;
            gather_kernel<<<(npix_chunk + 255) / 256, 256, 0, stream>>>(
                ws, out0, out1, n0, npix_chunk);
        }
    } else {
        const int threads = 256;
        const int blocks = (NPIX + threads - 1) / threads;
        splat_atomic_kernel<<<blocks, threads, 0, stream>>>(img, counts, flo,
                                                            out0, out1);
        finalize_kernel<<<blocks, threads, 0, stream>>>(out0, out1);
    }
}